// Round 5
// baseline (12886.864 us; speedup 1.0000x reference)
//
#include <hip/hip_runtime.h>

typedef unsigned short u16;
typedef unsigned int   u32;
typedef unsigned long long u64;
typedef __attribute__((ext_vector_type(8))) short  bf16x8;
typedef __attribute__((ext_vector_type(4))) float  f32x4;

#define B_   128
#define T_   1024
#define I_   64
#define H_   512
#define G4_  2048

#define NG_   8     // batch groups
#define BGRP_ 16    // batch rows per group
#define NBH_  16    // h-chunk blocks per group per layer
#define HC_   32    // h columns per chunk block
#define GCP_  131   // lds_g row stride (128 data + 3 pad, odd -> spreads banks)
#define R_    8     // inter-layer ring depth (power of 2)

__device__ __forceinline__ float b2f(u16 u){ return __uint_as_float(((u32)u)<<16); }
__device__ __forceinline__ u16  f2b(float f){ u32 u = __float_as_uint(f); return (u16)((u + 0x7fffu + ((u>>16)&1u))>>16); }
__device__ __forceinline__ float sigf(float x){ return 1.f/(1.f + __expf(-x)); }
__device__ __forceinline__ float tanh_f(float x){
    float a = fabsf(x); float e = __expf(-2.f*a);
    float r = (1.f-e)/(1.f+e); return x<0.f ? -r : r;
}
// XOR swizzle for 1024-byte LDS rows (read side verified vs MFMA frag layout)
__device__ __forceinline__ int swz(int row, int colbyte){ return row*1024 + (colbyte ^ ((row&7)<<4)); }

// load 8 consecutive fp32 -> bf16x8 fragment (16B-aligned source)
__device__ __forceinline__ bf16x8 ld8f(const float* p){
    float4 a = *(const float4*)p, b = *(const float4*)(p+4);
    bf16x8 r;
    r[0]=(short)f2b(a.x); r[1]=(short)f2b(a.y); r[2]=(short)f2b(a.z); r[3]=(short)f2b(a.w);
    r[4]=(short)f2b(b.x); r[5]=(short)f2b(b.y); r[6]=(short)f2b(b.z); r[7]=(short)f2b(b.w);
    return r;
}

#define MFMA(a,b,c) __builtin_amdgcn_mfma_f32_16x16x32_bf16((a),(b),(c),0,0,0)
#define ALD(p)   __hip_atomic_load((p),  __ATOMIC_RELAXED, __HIP_MEMORY_SCOPE_AGENT)
#define AST(p,v) __hip_atomic_store((p),(v),__ATOMIC_RELAXED, __HIP_MEMORY_SCOPE_AGENT)

// wave-flags: [2][NG_][NBH_][4] u32 — flag[layer][grp][chunk][rowgrp] = steps completed
static constexpr int N_FLG = 2*NG_*NBH_*4;   // 1024 words

// ---------------- h_init = (cond @ Wc^T + bc) @ Wi^T + bi ; also zero flags ----------------
__global__ void k_prep(const float* __restrict__ cond, const float* __restrict__ Wc,
                       const float* __restrict__ bc,   const float* __restrict__ Wi,
                       const float* __restrict__ bi,   u16* ring, u16* h1buf, u32* flg)
{
    __shared__ float cp[32];
    int b = blockIdx.x, tid = threadIdx.x;
    if (b < 2) flg[b*512 + tid] = 0u;
    if (tid < 32) {
        float s = bc[tid];
        #pragma unroll
        for (int i=0;i<10;++i) s += cond[b*10+i]*Wc[tid*10+i];
        cp[tid] = s;
    }
    __syncthreads();
    float s = bi[tid];
    #pragma unroll
    for (int c=0;c<32;++c) s += cp[c]*Wi[tid*32+c];
    u16 hv = f2b(s);
    ring [((size_t)(R_-1)*B_ + b)*H_ + tid] = hv;  // layer-0 recurrent init (slot R-1)
    h1buf[(size_t)b*H_ + tid]              = hv;  // layer-1 recurrent init (buffer 0)
}

// ---------------- fused 2-layer pipelined LSTM ----------------
// 256 blocks. grp = bid&7, layer = (bid>>3)>>4, chunk = (bid>>3)&15. 1 block/CU.
__global__ __launch_bounds__(256, 1)
void k_fused(const float* __restrict__ x,
             const float* __restrict__ Wih0f, const float* __restrict__ Whh0f,
             const float* __restrict__ Wih1f, const float* __restrict__ Whh1f,
             const float* __restrict__ bih0f, const float* __restrict__ bhh0f,
             const float* __restrict__ bih1f, const float* __restrict__ bhh1f,
             u16* ring,     // [R_][B][512] bf16 (layer-0 h + its own recurrence)
             u16* h1buf,    // [2][B][512] bf16 (layer-1 recurrence)
             u32* flagbase, // [2][NG_][NBH_][4]
             float* hlast)  // [B][512] f32
{
    __shared__ u16  lds_a[BGRP_*H_];    // 16KB swizzled
    __shared__ u16  lds_b[BGRP_*H_];    // 16KB swizzled
    __shared__ float lds_g[BGRP_*GCP_]; // gate staging (padded stride)

    const int tid = threadIdx.x;
    const int w = tid>>6, lane = tid&63;
    const int bid = blockIdx.x;
    const int grp = bid & 7;
    const int rest = bid >> 3;
    const int layer = rest >> 4, chunk = rest & 15;
    const int n0 = chunk*HC_;
    const int gb = grp*BGRP_;
    u32* fw0 = flagbase + grp*NBH_*4;                // layer-0 wave-flags for this group
    u32* fw1 = flagbase + NG_*NBH_*4 + grp*NBH_*4;   // layer-1 wave-flags

    // combine mapping: thread -> (batch row prow, h-cols phc, phc+1)
    const int prow = tid>>4;
    const int phc  = (2*tid)&31;
    // staging mapping: thread -> (row srow, u64 cols {16*i + jj})
    const int srow = tid>>4, jj = tid&15;
    const int rw = srow>>2;      // producer wave covering srow
    const int fb = jj>>3;        // chunk parity this thread touches

    // biases in registers (bih+bhh, fp32)
    const float* ba = (layer==0) ? bih0f : bih1f;
    const float* bb = (layer==0) ? bhh0f : bhh1f;
    float bias[8];
    #pragma unroll
    for (int q=0;q<4;++q){
        int idx = q*H_ + n0 + phc;
        bias[2*q]   = ba[idx]   + bb[idx];
        bias[2*q+1] = ba[idx+1] + bb[idx+1];
    }

    float c0 = 0.f, c1 = 0.f;

    // B-fragment gate-row indices for this wave's two 16-col N-tiles
    const int s0i = 2*w*16 + (lane&15), s1i = s0i+16;
    const int r0 = (s0i>>5)*H_ + n0 + (s0i&31);   // weight row (gate-major)
    const int r1 = (s1i>>5)*H_ + n0 + (s1i&31);
    const int kc = (lane>>4)*8;                   // k offset within frag

    if (layer == 0) {
        // ---- preload Whh0 (16x2 frags) + Wih0 (2x2 frags), fp32->bf16 in-register ----
        bf16x8 bh0[16], bh1[16], bx0[2], bx1[2];
        {
            const float* p0 = Whh0f + (size_t)r0*H_ + kc;
            const float* p1 = Whh0f + (size_t)r1*H_ + kc;
            #pragma unroll
            for (int kt=0;kt<16;++kt){ bh0[kt]=ld8f(p0+kt*32); bh1[kt]=ld8f(p1+kt*32); }
            const float* q0 = Wih0f + (size_t)r0*I_ + kc;
            const float* q1 = Wih0f + (size_t)r1*I_ + kc;
            #pragma unroll
            for (int kt=0;kt<2;++kt){ bx0[kt]=ld8f(q0+kt*32); bx1[kt]=ld8f(q1+kt*32); }
        }

        for (int t = 0; t < T_; ++t) {
            // prefetch x (independent of flags; HBM latency hides under polling)
            const float* xp = x + ((size_t)(gb+srow)*T_ + t)*I_ + jj*4;
            float4 xv = *(const float4*)xp;

            // poll (relaxed): my 8 chunks published step t for my row-group;
            // L1 consumed ring slot (wave-flags >= t-(R_-1))
            {
                const int need1 = t - (R_-1);
                for (;;) {
                    int ok = 1;
                    #pragma unroll
                    for (int i=0;i<8;++i) {
                        int c = 2*i + fb;
                        u32 a = ALD(&fw0[c*4 + rw]);
                        u32 b = ALD(&fw1[c*4 + rw]);
                        ok &= ((int)a >= t) & ((int)b >= need1);
                    }
                    if (ok) break;
                    __builtin_amdgcn_s_sleep(1);
                }
            }

            // x -> lds_b (swizzled 128B rows)
            {
                u16 a=f2b(xv.x), b=f2b(xv.y), c=f2b(xv.z), d=f2b(xv.w);
                u64 pk = (u64)((u32)a|((u32)b<<16)) | ((u64)((u32)c|((u32)d<<16))<<32);
                *(u64*)((char*)lds_b + srow*128 + ((jj*8) ^ ((srow&7)<<4))) = pk;
            }
            // stage h0[t-1] from ring slot (t-1)&(R-1), strided u64 for bank spread
            {
                const int ps = (t + R_ - 1) & (R_-1);
                const u64* src = (const u64*)(ring + ((size_t)ps*B_ + gb + srow)*H_);
                #pragma unroll
                for (int i=0;i<8;++i){
                    int cu = 16*i + jj;
                    u64 v = ALD((u64*)(src + cu));
                    *(u64*)((char*)lds_a + swz(srow, cu*8)) = v;
                }
            }
            __syncthreads();   // S2

            // gates = x @ Wih0^T + h @ Whh0^T
            f32x4 acc0 = {0.f,0.f,0.f,0.f}, acc1 = {0.f,0.f,0.f,0.f};
            #pragma unroll
            for (int kt=0;kt<2;++kt){
                bf16x8 a = *(const bf16x8*)((char*)lds_b + (lane&15)*128 + ((kt*64 + (lane>>4)*16) ^ ((lane&7)<<4)));
                acc0 = MFMA(a, bx0[kt], acc0);
                acc1 = MFMA(a, bx1[kt], acc1);
            }
            #pragma unroll
            for (int kt=0;kt<16;++kt){
                bf16x8 a = *(const bf16x8*)((char*)lds_a + swz(lane&15, kt*64 + (lane>>4)*16));
                acc0 = MFMA(a, bh0[kt], acc0);
                acc1 = MFMA(a, bh1[kt], acc1);
            }
            {
                int gr=(lane>>4)*4, gc=lane&15;
                #pragma unroll
                for (int j=0;j<4;++j){
                    lds_g[(gr+j)*GCP_ + 2*w*16      + gc] = acc0[j];
                    lds_g[(gr+j)*GCP_ + (2*w+1)*16  + gc] = acc1[j];
                }
            }
            __syncthreads();   // S3

            // combine -> h0[t] into ring slot t&(R-1); per-wave flag publish
            {
                float2 gi = *(const float2*)&lds_g[prow*GCP_ +      phc];
                float2 gf = *(const float2*)&lds_g[prow*GCP_ + 32 + phc];
                float2 gg = *(const float2*)&lds_g[prow*GCP_ + 64 + phc];
                float2 go = *(const float2*)&lds_g[prow*GCP_ + 96 + phc];
                c0 = sigf(gf.x+bias[2])*c0 + sigf(gi.x+bias[0])*tanh_f(gg.x+bias[4]);
                c1 = sigf(gf.y+bias[3])*c1 + sigf(gi.y+bias[1])*tanh_f(gg.y+bias[5]);
                float h0v = sigf(go.x+bias[6])*tanh_f(c0);
                float h1v = sigf(go.y+bias[7])*tanh_f(c1);
                u32 pack = (u32)f2b(h0v) | ((u32)f2b(h1v)<<16);
                const int cs = t & (R_-1);
                AST((u32*)(ring + ((size_t)cs*B_ + gb + prow)*H_ + n0 + phc), pack);
            }
            asm volatile("s_waitcnt vmcnt(0)" ::: "memory");  // per-wave drain to MALL
            if (lane == 0)
                AST(&fw0[chunk*4 + w], (u32)(t+1));
        }
    } else {
        // ---- preload Wih1 + Whh1 (16x2 frags each = 256 VGPR), fp32->bf16 in-register ----
        bf16x8 bi0[16], bi1[16], bh0[16], bh1[16];
        {
            const float* p0 = Wih1f + (size_t)r0*H_ + kc;
            const float* p1 = Wih1f + (size_t)r1*H_ + kc;
            const float* q0 = Whh1f + (size_t)r0*H_ + kc;
            const float* q1 = Whh1f + (size_t)r1*H_ + kc;
            #pragma unroll
            for (int kt=0;kt<16;++kt){
                bi0[kt]=ld8f(p0+kt*32); bi1[kt]=ld8f(p1+kt*32);
                bh0[kt]=ld8f(q0+kt*32); bh1[kt]=ld8f(q1+kt*32);
            }
        }

        for (int t = 0; t < T_; ++t) {
            // poll (relaxed): L0 published step t (flags >= t+1); peers published t-1 (>= t)
            for (;;) {
                int ok = 1;
                #pragma unroll
                for (int i=0;i<8;++i) {
                    int c = 2*i + fb;
                    u32 a = ALD(&fw0[c*4 + rw]);
                    u32 b = ALD(&fw1[c*4 + rw]);
                    ok &= ((int)a >= t+1) & ((int)b >= t);
                }
                if (ok) break;
                __builtin_amdgcn_s_sleep(1);
            }

            // stage h0[t] (ring slot t&(R-1)) -> lds_a ; h1[t-1] (h1buf[t&1]) -> lds_b
            {
                const int cs = t & (R_-1);
                const u64* sa_ = (const u64*)(ring  + ((size_t)cs*B_    + gb + srow)*H_);
                const u64* sb_ = (const u64*)(h1buf + ((size_t)(t&1)*B_ + gb + srow)*H_);
                #pragma unroll
                for (int i=0;i<8;++i){
                    int cu = 16*i + jj;
                    u64 v = ALD((u64*)(sa_ + cu));
                    *(u64*)((char*)lds_a + swz(srow, cu*8)) = v;
                }
                #pragma unroll
                for (int i=0;i<8;++i){
                    int cu = 16*i + jj;
                    u64 v = ALD((u64*)(sb_ + cu));
                    *(u64*)((char*)lds_b + swz(srow, cu*8)) = v;
                }
            }
            __syncthreads();   // S2

            // gates = h0_in @ Wih1^T + h1_prev @ Whh1^T
            f32x4 acc0 = {0.f,0.f,0.f,0.f}, acc1 = {0.f,0.f,0.f,0.f};
            #pragma unroll
            for (int kt=0;kt<16;++kt){
                bf16x8 a0 = *(const bf16x8*)((char*)lds_a + swz(lane&15, kt*64 + (lane>>4)*16));
                bf16x8 a1 = *(const bf16x8*)((char*)lds_b + swz(lane&15, kt*64 + (lane>>4)*16));
                acc0 = MFMA(a0, bi0[kt], acc0);
                acc1 = MFMA(a0, bi1[kt], acc1);
                acc0 = MFMA(a1, bh0[kt], acc0);
                acc1 = MFMA(a1, bh1[kt], acc1);
            }
            {
                int gr=(lane>>4)*4, gc=lane&15;
                #pragma unroll
                for (int j=0;j<4;++j){
                    lds_g[(gr+j)*GCP_ + 2*w*16      + gc] = acc0[j];
                    lds_g[(gr+j)*GCP_ + (2*w+1)*16  + gc] = acc1[j];
                }
            }
            __syncthreads();   // S3

            // combine -> h1 into h1buf[(t+1)&1]; last step -> hlast fp32
            {
                float2 gi = *(const float2*)&lds_g[prow*GCP_ +      phc];
                float2 gf = *(const float2*)&lds_g[prow*GCP_ + 32 + phc];
                float2 gg = *(const float2*)&lds_g[prow*GCP_ + 64 + phc];
                float2 go = *(const float2*)&lds_g[prow*GCP_ + 96 + phc];
                c0 = sigf(gf.x+bias[2])*c0 + sigf(gi.x+bias[0])*tanh_f(gg.x+bias[4]);
                c1 = sigf(gf.y+bias[3])*c1 + sigf(gi.y+bias[1])*tanh_f(gg.y+bias[5]);
                float h0v = sigf(go.x+bias[6])*tanh_f(c0);
                float h1v = sigf(go.y+bias[7])*tanh_f(c1);
                u32 pack = (u32)f2b(h0v) | ((u32)f2b(h1v)<<16);
                AST((u32*)(h1buf + ((size_t)((t+1)&1)*B_ + gb + prow)*H_ + n0 + phc), pack);
                if (t == T_-1) {
                    hlast[(size_t)(gb+prow)*H_ + n0 + phc    ] = h0v;
                    hlast[(size_t)(gb+prow)*H_ + n0 + phc + 1] = h1v;
                }
            }
            asm volatile("s_waitcnt vmcnt(0)" ::: "memory");  // per-wave drain to MALL
            if (lane == 0)
                AST(&fw1[chunk*4 + w], (u32)(t+1));
        }
    }
}

// ---------------- output head ----------------
__global__ void k_out(const float* __restrict__ hlast, const float* __restrict__ Wout,
                      const float* __restrict__ bout, float* __restrict__ y)
{
    int b = blockIdx.x;
    int w = threadIdx.x>>6, lane = threadIdx.x&63;
    const float* hp = hlast + (size_t)b*H_;
    #pragma unroll
    for (int oo=0; oo<4; ++oo) {
        int o = w*4 + oo;
        const float* wp = Wout + (size_t)o*H_;
        float p = 0.f;
        for (int k=lane; k<H_; k+=64) p += hp[k]*wp[k];
        #pragma unroll
        for (int off=32; off; off>>=1) p += __shfl_down(p, off);
        if (lane==0) y[b*16 + o] = p + bout[o];
    }
}

// ---------------- workspace layout (total ~2.8MB) ----------------
static constexpr size_t OFF_RING = 0;
static constexpr size_t OFF_H1   = OFF_RING + (size_t)R_*B_*H_*2;  // 1MB
static constexpr size_t OFF_HL   = OFF_H1   + (size_t)2*B_*H_*2;   // 256KB
static constexpr size_t OFF_FLG  = OFF_HL   + (size_t)B_*H_*4;     // 256KB

extern "C" void kernel_launch(void* const* d_in, const int* in_sizes, int n_in,
                              void* d_out, int out_size, void* d_ws, size_t ws_size,
                              hipStream_t stream)
{
    (void)in_sizes; (void)n_in; (void)out_size; (void)ws_size;
    const float* x    = (const float*)d_in[0];
    const float* cond = (const float*)d_in[1];
    const float* Wc   = (const float*)d_in[2];
    const float* bc   = (const float*)d_in[3];
    const float* Wi   = (const float*)d_in[4];
    const float* bi   = (const float*)d_in[5];
    const float* Wih0 = (const float*)d_in[6];
    const float* Whh0 = (const float*)d_in[7];
    const float* bih0 = (const float*)d_in[8];
    const float* bhh0 = (const float*)d_in[9];
    const float* Wih1 = (const float*)d_in[10];
    const float* Whh1 = (const float*)d_in[11];
    const float* bih1 = (const float*)d_in[12];
    const float* bhh1 = (const float*)d_in[13];
    const float* Wout = (const float*)d_in[14];
    const float* bout = (const float*)d_in[15];
    float* y = (float*)d_out;
    char* ws = (char*)d_ws;

    u16* ring  = (u16*)(ws + OFF_RING);
    u16* h1b   = (u16*)(ws + OFF_H1);
    float* hl  = (float*)(ws + OFF_HL);
    u32* flg   = (u32*)(ws + OFF_FLG);

    k_prep<<<B_, 512, 0, stream>>>(cond, Wc, bc, Wi, bi, ring, h1b, flg);

    k_fused<<<2*NBH_*NG_, 256, 0, stream>>>(x, Wih0, Whh0, Wih1, Whh1,
                                            bih0, bhh0, bih1, bhh1,
                                            ring, h1b, flg, hl);

    k_out<<<B_, 256, 0, stream>>>(hl, Wout, bout, y);
}

// Round 6
// 5811.412 us; speedup vs baseline: 2.2175x; 2.2175x over previous
//
#include <hip/hip_runtime.h>

typedef unsigned short u16;
typedef unsigned int   u32;
typedef unsigned long long u64;
typedef __attribute__((ext_vector_type(8))) short  bf16x8;
typedef __attribute__((ext_vector_type(4))) float  f32x4;

#define B_   128
#define T_   1024
#define I_   64
#define H_   512
#define G4_  2048

#define NG_   8     // batch groups
#define BGRP_ 16    // batch rows per group
#define NBH_  16    // h-chunk blocks per group per layer
#define HC_   32    // h columns per chunk block
#define GCP_  131   // lds_g row stride (128 data + 3 pad)
#define R_    8     // ring depth (power of 2)

__device__ __forceinline__ u16  f2b(float f){ u32 u = __float_as_uint(f); return (u16)((u + 0x7fffu + ((u>>16)&1u))>>16); }
__device__ __forceinline__ float sigf(float x){ return 1.f/(1.f + __expf(-x)); }
__device__ __forceinline__ float tanh_f(float x){
    float a = fabsf(x); float e = __expf(-2.f*a);
    float r = (1.f-e)/(1.f+e); return x<0.f ? -r : r;
}
// XOR swizzle for 1024-byte LDS rows
__device__ __forceinline__ int swz(int row, int colbyte){ return row*1024 + (colbyte ^ ((row&7)<<4)); }

// load 8 consecutive fp32 -> bf16x8 fragment
__device__ __forceinline__ bf16x8 ld8f(const float* p){
    float4 a = *(const float4*)p, b = *(const float4*)(p+4);
    bf16x8 r;
    r[0]=(short)f2b(a.x); r[1]=(short)f2b(a.y); r[2]=(short)f2b(a.z); r[3]=(short)f2b(a.w);
    r[4]=(short)f2b(b.x); r[5]=(short)f2b(b.y); r[6]=(short)f2b(b.z); r[7]=(short)f2b(b.w);
    return r;
}

#define MFMA(a,b,c) __builtin_amdgcn_mfma_f32_16x16x32_bf16((a),(b),(c),0,0,0)
#define ALD(p)   __hip_atomic_load((p),  __ATOMIC_RELAXED, __HIP_MEMORY_SCOPE_AGENT)
#define AST(p,v) __hip_atomic_store((p),(v),__ATOMIC_RELAXED, __HIP_MEMORY_SCOPE_AGENT)

// ---------------- h_init; tagged ring slot R-1 (tag 0); zero L1-progress flags ----------------
__global__ void k_prep(const float* __restrict__ cond, const float* __restrict__ Wc,
                       const float* __restrict__ bc,   const float* __restrict__ Wi,
                       const float* __restrict__ bi,   u32* h0r, u32* h1r, u32* prog)
{
    __shared__ float cp[32];
    int b = blockIdx.x, tid = threadIdx.x;
    if (b == 0 && tid < NG_*NBH_) prog[tid] = 0u;
    if (tid < 32) {
        float s = bc[tid];
        #pragma unroll
        for (int i=0;i<10;++i) s += cond[b*10+i]*Wc[tid*10+i];
        cp[tid] = s;
    }
    __syncthreads();
    float s = bi[tid];
    #pragma unroll
    for (int c=0;c<32;++c) s += cp[c]*Wi[tid*32+c];
    u32 v = (u32)f2b(s);                        // tag 0 in hi16
    h0r[((size_t)(R_-1)*B_ + b)*H_ + tid] = v;  // layer-0 recurrent init
    h1r[((size_t)(R_-1)*B_ + b)*H_ + tid] = v;  // layer-1 recurrent init
}

// ---------------- fused 2-layer pipelined LSTM, tagged-data sync ----------------
// 256 blocks. grp = bid&7, layer = (bid>>3)>>4, chunk = (bid>>3)&15. 1 block/CU.
// h rings hold u32 = (tag<<16)|bf16 ; tag for h produced at step u is u+1.
__global__ __launch_bounds__(256, 1)
void k_fused(const float* __restrict__ x,
             const float* __restrict__ Wih0f, const float* __restrict__ Whh0f,
             const float* __restrict__ Wih1f, const float* __restrict__ Whh1f,
             const float* __restrict__ bih0f, const float* __restrict__ bhh0f,
             const float* __restrict__ bih1f, const float* __restrict__ bhh1f,
             u32* h0r,      // [R_][B][512] tagged bf16
             u32* h1r,      // [R_][B][512] tagged bf16
             u32* progbase, // [NG_][NBH_]  L1 staging progress (backpressure only)
             float* hlast)  // [B][512] f32
{
    __shared__ u16  lds_a[BGRP_*H_];    // 16KB swizzled
    __shared__ u16  lds_b[BGRP_*H_];    // 16KB swizzled
    __shared__ float lds_g[BGRP_*GCP_]; // gate staging

    const int tid = threadIdx.x;
    const int w = tid>>6, lane = tid&63;
    const int bid = blockIdx.x;
    const int grp = bid & 7;
    const int rest = bid >> 3;
    const int layer = rest >> 4, chunk = rest & 15;
    const int n0 = chunk*HC_;
    const int gb = grp*BGRP_;
    u32* prog = progbase + grp*NBH_;

    const int prow = tid>>4;
    const int phc  = (2*tid)&31;
    const int srow = tid>>4, jj = tid&15;

    const float* ba = (layer==0) ? bih0f : bih1f;
    const float* bb = (layer==0) ? bhh0f : bhh1f;
    float bias[8];
    #pragma unroll
    for (int q=0;q<4;++q){
        int idx = q*H_ + n0 + phc;
        bias[2*q]   = ba[idx]   + bb[idx];
        bias[2*q+1] = ba[idx+1] + bb[idx+1];
    }

    float c0 = 0.f, c1 = 0.f;

    const int s0i = 2*w*16 + (lane&15), s1i = s0i+16;
    const int r0 = (s0i>>5)*H_ + n0 + (s0i&31);
    const int r1 = (s1i>>5)*H_ + n0 + (s1i&31);
    const int kc = (lane>>4)*8;

    if (layer == 0) {
        bf16x8 bh0[16], bh1[16], bx0[2], bx1[2];
        {
            const float* p0 = Whh0f + (size_t)r0*H_ + kc;
            const float* p1 = Whh0f + (size_t)r1*H_ + kc;
            #pragma unroll
            for (int kt=0;kt<16;++kt){ bh0[kt]=ld8f(p0+kt*32); bh1[kt]=ld8f(p1+kt*32); }
            const float* q0 = Wih0f + (size_t)r0*I_ + kc;
            const float* q1 = Wih0f + (size_t)r1*I_ + kc;
            #pragma unroll
            for (int kt=0;kt<2;++kt){ bx0[kt]=ld8f(q0+kt*32); bx1[kt]=ld8f(q1+kt*32); }
        }

        for (int t = 0; t < T_; ++t) {
            // x prefetch (overlaps everything below)
            const float* xp = x + ((size_t)(gb+srow)*T_ + t)*I_ + jj*4;
            float4 xv = *(const float4*)xp;

            // speculative stage of h0[t-1]: slot (t-1)&7, expect tag t
            const int ps = (t + R_ - 1) & (R_-1);
            const u32 tagv = (u32)t;
            const u32* src = h0r + ((size_t)ps*B_ + gb + srow)*H_;
            u32 va[16], vb[16];
            #pragma unroll
            for (int i=0;i<16;++i){ int p = 16*i + jj; va[i]=ALD(src+2*p); vb[i]=ALD(src+2*p+1); }

            // backpressure: L1 staged step t-(R-1) (almost always already true)
            if (tid < 16) {
                const int need = t - (R_-1);
                while ((int)ALD(&prog[tid]) < need) __builtin_amdgcn_s_sleep(1);
            }

            // validate tags; retry until all match
            for (;;) {
                int ok = 1;
                #pragma unroll
                for (int i=0;i<16;++i){
                    ok = ok & (int)((va[i]>>16) == tagv) & (int)((vb[i]>>16) == tagv);
                }
                if (ok) break;
                __builtin_amdgcn_s_sleep(1);
                #pragma unroll
                for (int i=0;i<16;++i){ int p=16*i+jj; va[i]=ALD(src+2*p); vb[i]=ALD(src+2*p+1); }
            }
            // h -> lds_a (packed pairs, swizzled)
            #pragma unroll
            for (int i=0;i<16;++i){
                int p = 16*i + jj;
                u32 wv = (va[i]&0xffffu) | (vb[i]<<16);
                *(u32*)((char*)lds_a + swz(srow, p*4)) = wv;
            }
            // x -> lds_b
            {
                u16 a=f2b(xv.x), b=f2b(xv.y), c=f2b(xv.z), d=f2b(xv.w);
                u64 pk = (u64)((u32)a|((u32)b<<16)) | ((u64)((u32)c|((u32)d<<16))<<32);
                *(u64*)((char*)lds_b + srow*128 + ((jj*8) ^ ((srow&7)<<4))) = pk;
            }
            __syncthreads();   // S2

            f32x4 acc0 = {0.f,0.f,0.f,0.f}, acc1 = {0.f,0.f,0.f,0.f};
            #pragma unroll
            for (int kt=0;kt<2;++kt){
                bf16x8 a = *(const bf16x8*)((char*)lds_b + (lane&15)*128 + ((kt*64 + (lane>>4)*16) ^ ((lane&7)<<4)));
                acc0 = MFMA(a, bx0[kt], acc0);
                acc1 = MFMA(a, bx1[kt], acc1);
            }
            #pragma unroll
            for (int kt=0;kt<16;++kt){
                bf16x8 a = *(const bf16x8*)((char*)lds_a + swz(lane&15, kt*64 + (lane>>4)*16));
                acc0 = MFMA(a, bh0[kt], acc0);
                acc1 = MFMA(a, bh1[kt], acc1);
            }
            {
                int gr=(lane>>4)*4, gc=lane&15;
                #pragma unroll
                for (int j=0;j<4;++j){
                    lds_g[(gr+j)*GCP_ + 2*w*16      + gc] = acc0[j];
                    lds_g[(gr+j)*GCP_ + (2*w+1)*16  + gc] = acc1[j];
                }
            }
            __syncthreads();   // S3

            // combine -> tagged h0[t] into slot t&7 (no drain, no flag)
            {
                float2 gi = *(const float2*)&lds_g[prow*GCP_ +      phc];
                float2 gf = *(const float2*)&lds_g[prow*GCP_ + 32 + phc];
                float2 gg = *(const float2*)&lds_g[prow*GCP_ + 64 + phc];
                float2 go = *(const float2*)&lds_g[prow*GCP_ + 96 + phc];
                c0 = sigf(gf.x+bias[2])*c0 + sigf(gi.x+bias[0])*tanh_f(gg.x+bias[4]);
                c1 = sigf(gf.y+bias[3])*c1 + sigf(gi.y+bias[1])*tanh_f(gg.y+bias[5]);
                float h0v = sigf(go.x+bias[6])*tanh_f(c0);
                float h1v = sigf(go.y+bias[7])*tanh_f(c1);
                const int cs = t & (R_-1);
                u32* dst = h0r + ((size_t)cs*B_ + gb + prow)*H_ + n0 + phc;
                const u32 tg = (u32)(t+1)<<16;
                AST(dst,     tg | (u32)f2b(h0v));
                AST(dst + 1, tg | (u32)f2b(h1v));
            }
        }
    } else {
        bf16x8 bi0[16], bi1[16], bh0[16], bh1[16];
        {
            const float* p0 = Wih1f + (size_t)r0*H_ + kc;
            const float* p1 = Wih1f + (size_t)r1*H_ + kc;
            const float* q0 = Whh1f + (size_t)r0*H_ + kc;
            const float* q1 = Whh1f + (size_t)r1*H_ + kc;
            #pragma unroll
            for (int kt=0;kt<16;++kt){
                bi0[kt]=ld8f(p0+kt*32); bi1[kt]=ld8f(p1+kt*32);
                bh0[kt]=ld8f(q0+kt*32); bh1[kt]=ld8f(q1+kt*32);
            }
        }

        for (int t = 0; t < T_; ++t) {
            // speculative stage: h0[t] slot t&7 expect tag t+1 ; h1[t-1] slot (t-1)&7 expect tag t
            const int cs0 = t & (R_-1);
            const int ps1 = (t + R_ - 1) & (R_-1);
            const u32 tg0 = (u32)(t+1), tg1 = (u32)t;
            const u32* s0 = h0r + ((size_t)cs0*B_ + gb + srow)*H_;
            const u32* s1 = h1r + ((size_t)ps1*B_ + gb + srow)*H_;
            u32 va[16], vb[16], wa[16], wb[16];
            #pragma unroll
            for (int i=0;i<16;++i){ int p = 16*i + jj; va[i]=ALD(s0+2*p); vb[i]=ALD(s0+2*p+1); }
            #pragma unroll
            for (int i=0;i<16;++i){ int p = 16*i + jj; wa[i]=ALD(s1+2*p); wb[i]=ALD(s1+2*p+1); }

            for (;;) {
                int ok = 1;
                #pragma unroll
                for (int i=0;i<16;++i){
                    ok = ok & (int)((va[i]>>16) == tg0) & (int)((vb[i]>>16) == tg0);
                }
                if (ok) break;
                __builtin_amdgcn_s_sleep(1);
                #pragma unroll
                for (int i=0;i<16;++i){ int p=16*i+jj; va[i]=ALD(s0+2*p); vb[i]=ALD(s0+2*p+1); }
            }
            #pragma unroll
            for (int i=0;i<16;++i){
                int p = 16*i + jj;
                u32 wv = (va[i]&0xffffu) | (vb[i]<<16);
                *(u32*)((char*)lds_a + swz(srow, p*4)) = wv;
            }
            for (;;) {
                int ok = 1;
                #pragma unroll
                for (int i=0;i<16;++i){
                    ok = ok & (int)((wa[i]>>16) == tg1) & (int)((wb[i]>>16) == tg1);
                }
                if (ok) break;
                __builtin_amdgcn_s_sleep(1);
                #pragma unroll
                for (int i=0;i<16;++i){ int p=16*i+jj; wa[i]=ALD(s1+2*p); wb[i]=ALD(s1+2*p+1); }
            }
            #pragma unroll
            for (int i=0;i<16;++i){
                int p = 16*i + jj;
                u32 wv = (wa[i]&0xffffu) | (wb[i]<<16);
                *(u32*)((char*)lds_b + swz(srow, p*4)) = wv;
            }
            __syncthreads();   // S2

            // publish staging progress (backpressure for L0's slot reuse)
            if (tid == 0) AST(&prog[chunk], (u32)(t+1));

            f32x4 acc0 = {0.f,0.f,0.f,0.f}, acc1 = {0.f,0.f,0.f,0.f};
            #pragma unroll
            for (int kt=0;kt<16;++kt){
                bf16x8 a0 = *(const bf16x8*)((char*)lds_a + swz(lane&15, kt*64 + (lane>>4)*16));
                bf16x8 a1 = *(const bf16x8*)((char*)lds_b + swz(lane&15, kt*64 + (lane>>4)*16));
                acc0 = MFMA(a0, bi0[kt], acc0);
                acc1 = MFMA(a0, bi1[kt], acc1);
                acc0 = MFMA(a1, bh0[kt], acc0);
                acc1 = MFMA(a1, bh1[kt], acc1);
            }
            {
                int gr=(lane>>4)*4, gc=lane&15;
                #pragma unroll
                for (int j=0;j<4;++j){
                    lds_g[(gr+j)*GCP_ + 2*w*16      + gc] = acc0[j];
                    lds_g[(gr+j)*GCP_ + (2*w+1)*16  + gc] = acc1[j];
                }
            }
            __syncthreads();   // S3

            {
                float2 gi = *(const float2*)&lds_g[prow*GCP_ +      phc];
                float2 gf = *(const float2*)&lds_g[prow*GCP_ + 32 + phc];
                float2 gg = *(const float2*)&lds_g[prow*GCP_ + 64 + phc];
                float2 go = *(const float2*)&lds_g[prow*GCP_ + 96 + phc];
                c0 = sigf(gf.x+bias[2])*c0 + sigf(gi.x+bias[0])*tanh_f(gg.x+bias[4]);
                c1 = sigf(gf.y+bias[3])*c1 + sigf(gi.y+bias[1])*tanh_f(gg.y+bias[5]);
                float h0v = sigf(go.x+bias[6])*tanh_f(c0);
                float h1v = sigf(go.y+bias[7])*tanh_f(c1);
                const int cs = t & (R_-1);
                u32* dst = h1r + ((size_t)cs*B_ + gb + prow)*H_ + n0 + phc;
                const u32 tg = (u32)(t+1)<<16;
                AST(dst,     tg | (u32)f2b(h0v));
                AST(dst + 1, tg | (u32)f2b(h1v));
                if (t == T_-1) {
                    hlast[(size_t)(gb+prow)*H_ + n0 + phc    ] = h0v;
                    hlast[(size_t)(gb+prow)*H_ + n0 + phc + 1] = h1v;
                }
            }
        }
    }
}

// ---------------- output head ----------------
__global__ void k_out(const float* __restrict__ hlast, const float* __restrict__ Wout,
                      const float* __restrict__ bout, float* __restrict__ y)
{
    int b = blockIdx.x;
    int w = threadIdx.x>>6, lane = threadIdx.x&63;
    const float* hp = hlast + (size_t)b*H_;
    #pragma unroll
    for (int oo=0; oo<4; ++oo) {
        int o = w*4 + oo;
        const float* wp = Wout + (size_t)o*H_;
        float p = 0.f;
        for (int k=lane; k<H_; k+=64) p += hp[k]*wp[k];
        #pragma unroll
        for (int off=32; off; off>>=1) p += __shfl_down(p, off);
        if (lane==0) y[b*16 + o] = p + bout[o];
    }
}

// ---------------- workspace layout (~4.3MB) ----------------
static constexpr size_t OFF_H0R = 0;
static constexpr size_t OFF_H1R = OFF_H0R + (size_t)R_*B_*H_*4;  // 2MB
static constexpr size_t OFF_HL  = OFF_H1R + (size_t)R_*B_*H_*4;  // 2MB
static constexpr size_t OFF_PRG = OFF_HL  + (size_t)B_*H_*4;     // 256KB

extern "C" void kernel_launch(void* const* d_in, const int* in_sizes, int n_in,
                              void* d_out, int out_size, void* d_ws, size_t ws_size,
                              hipStream_t stream)
{
    (void)in_sizes; (void)n_in; (void)out_size; (void)ws_size;
    const float* x    = (const float*)d_in[0];
    const float* cond = (const float*)d_in[1];
    const float* Wc   = (const float*)d_in[2];
    const float* bc   = (const float*)d_in[3];
    const float* Wi   = (const float*)d_in[4];
    const float* bi   = (const float*)d_in[5];
    const float* Wih0 = (const float*)d_in[6];
    const float* Whh0 = (const float*)d_in[7];
    const float* bih0 = (const float*)d_in[8];
    const float* bhh0 = (const float*)d_in[9];
    const float* Wih1 = (const float*)d_in[10];
    const float* Whh1 = (const float*)d_in[11];
    const float* bih1 = (const float*)d_in[12];
    const float* bhh1 = (const float*)d_in[13];
    const float* Wout = (const float*)d_in[14];
    const float* bout = (const float*)d_in[15];
    float* y = (float*)d_out;
    char* ws = (char*)d_ws;

    u32* h0r  = (u32*)(ws + OFF_H0R);
    u32* h1r  = (u32*)(ws + OFF_H1R);
    float* hl = (float*)(ws + OFF_HL);
    u32* prg  = (u32*)(ws + OFF_PRG);

    k_prep<<<B_, 512, 0, stream>>>(cond, Wc, bc, Wi, bi, h0r, h1r, prg);

    k_fused<<<2*NBH_*NG_, 256, 0, stream>>>(x, Wih0, Whh0, Wih1, Whh1,
                                            bih0, bhh0, bih1, bhh1,
                                            h0r, h1r, prg, hl);

    k_out<<<B_, 256, 0, stream>>>(hl, Wout, bout, y);
}